// Round 9
// baseline (340.716 us; speedup 1.0000x reference)
//
#include <hip/hip_runtime.h>

// GateRecurrent2dnoind: left-to-right SPN scan over W, 3-pt stencil along H.
// [N=8, C=64, H=256, W=256] fp32.
//
// R9 = R8 with the two measured defects fixed:
//  (1) FETCH 1.87x -> ideal: WT=16, staging instruction = 4 lanes x float4 =
//      full 64B line per row per instruction (R1's proven-ideal profile).
//  (2) 4.2M LDS bank-conflict cycles + scalar-store bloat -> all sb traffic
//      is ds_{write,read}_b128 with XOR slot swizzle
//      phys = s ^ (row&3) ^ ((row>>2)&3)  (derived conflict-free both sides).
// Single sb buffer (66KB -> 2 blocks/CU); double-buffering lives in regs:
//   preload(q from sb) -> barrier -> stage(t+1: reg->LDS) -> issue(t+2:
//   global->reg) -> 16 scan steps (hbuf barriers double as visibility fence).
// Scan core identical to R8 (hbuf publish/read, 1 barrier per step).

constexpr int H  = 256;
constexpr int W  = 256;
constexpr int WT = 16;
constexpr int NT = W / WT;      // 16 tiles

__global__ __launch_bounds__(256, 2)
void spn_block(const float* __restrict__ X,  const float* __restrict__ G1,
               const float* __restrict__ G2, const float* __restrict__ G3,
               float* __restrict__ O)
{
    __shared__ float4 sb[4][256][4];     // [array][row][phys slot] = 64 KiB
    __shared__ float  hb[2][258];        // zero-padded neighbor-exchange line

    const int    t  = threadIdx.x;       // row index 0..255
    const size_t pb = (size_t)blockIdx.x * (size_t)(H * W);
    const float* __restrict__ a0 = X  + pb;
    const float* __restrict__ a1 = G1 + pb;
    const float* __restrict__ a2 = G2 + pb;
    const float* __restrict__ a3 = G3 + pb;

    // staging mapping: pass p covers row p*64 + (t>>2); lanes 4r..4r+3 cover
    // 64B contiguous -> every fetched line fully covered by ONE instruction.
    const int srow0 = t >> 2;
    const int scol  = (t & 3) << 2;
    // store swizzle (pass-independent): s=(t&3), row&3=(t>>2)&3, (row>>2)&3=(t>>4)&3
    const int wps   = (t & 3) ^ ((t >> 2) & 3) ^ ((t >> 4) & 3);
    // read swizzle keys for row t
    const int rk    = (t & 3) ^ ((t >> 2) & 3);

    float4 rg[4][4];                     // [array][pass] — next tile in regs

    auto issue = [&](int tile) {
        const int w0 = tile * WT + scol;
#pragma unroll
        for (int p = 0; p < 4; ++p) {
            const size_t off = (size_t)(p * 64 + srow0) * W + w0;
            rg[0][p] = *reinterpret_cast<const float4*>(a0 + off);
            rg[1][p] = *reinterpret_cast<const float4*>(a1 + off);
            rg[2][p] = *reinterpret_cast<const float4*>(a2 + off);
            rg[3][p] = *reinterpret_cast<const float4*>(a3 + off);
        }
    };
    auto stage = [&]() {
#pragma unroll
        for (int p = 0; p < 4; ++p) {
            const int row = p * 64 + srow0;
#pragma unroll
            for (int a = 0; a < 4; ++a)
                sb[a][row][wps] = rg[a][p];
        }
    };

    // boundary zeros (visible after the prologue barrier, never overwritten)
    if (t < 2) { hb[t][0] = 0.f; hb[t][257] = 0.f; }

    issue(0);
    stage();                             // sb <- tile 0 (vmcnt dep auto-waited)
    issue(1);                            // rg <- tile 1
    __syncthreads();

    float h = 0.f;
    float* __restrict__ orow = O + pb + (size_t)t * W;

#pragma unroll 1
    for (int tile = 0; tile < NT; ++tile) {
        // ---- preload row t's 16 operands x 4 arrays (b128, conflict-free) ----
        float4 q[4][4];                  // [array][logical slot]
#pragma unroll
        for (int j = 0; j < 4; ++j) {
            const int ps = j ^ rk;
            q[0][j] = sb[0][t][ps];
            q[1][j] = sb[1][t][ps];
            q[2][j] = sb[2][t][ps];
            q[3][j] = sb[3][t][ps];
        }
        __syncthreads();                 // all preload reads done before overwrite

        if (tile + 1 < NT) stage();      // reg -> LDS (tile+1)
        if (tile + 2 < NT) issue(tile + 2);  // global -> reg (tile+2)
        // visibility of stage() to next preload: fenced by the 16 scan barriers

        // ---- 16 sequential scan steps ----
        float4 of[4];
#pragma unroll
        for (int ww = 0; ww < 16; ++ww) {
            float* hp = hb[ww & 1];
            hp[t + 1] = h;               // publish h_prev
            __syncthreads();
            const float hu = hp[t], hd = hp[t + 2];
            const float x  = (&q[0][ww >> 2].x)[ww & 3];
            const float g1 = (&q[1][ww >> 2].x)[ww & 3];
            const float g2 = (&q[2][ww >> 2].x)[ww & 3];
            const float g3 = (&q[3][ww >> 2].x)[ww & 3];
            h = fmaf(g3, hd, fmaf(g2, h, fmaf(g1, hu,
                     x * (1.f - g1 - g2 - g3))));
            (&of[ww >> 2].x)[ww & 3] = h;
        }

        // ---- store 16 cols (full 64B contiguous per row) ----
        float* po = orow + tile * WT;
        *reinterpret_cast<float4*>(po +  0) = of[0];
        *reinterpret_cast<float4*>(po +  4) = of[1];
        *reinterpret_cast<float4*>(po +  8) = of[2];
        *reinterpret_cast<float4*>(po + 12) = of[3];
    }
}

extern "C" void kernel_launch(void* const* d_in, const int* in_sizes, int n_in,
                              void* d_out, int out_size, void* d_ws, size_t ws_size,
                              hipStream_t stream) {
    const float* X  = (const float*)d_in[0];
    const float* G1 = (const float*)d_in[1];
    const float* G2 = (const float*)d_in[2];
    const float* G3 = (const float*)d_in[3];
    float* O = (float*)d_out;

    const int planes = 8 * 64;   // 512 blocks, 2 per CU, one resident round
    spn_block<<<dim3(planes), dim3(256), 0, stream>>>(X, G1, G2, G3, O);
}